// Round 5
// baseline (541.847 us; speedup 1.0000x reference)
//
#include <hip/hip_runtime.h>
#include <stdint.h>

typedef unsigned short u16;
typedef __attribute__((ext_vector_type(8))) short short8;
typedef __attribute__((ext_vector_type(4))) float f32x4;

#define S_LEN 3072
#define D_DIM 2048
#define WIN 768
#define INV_SQRT_HD 0.08838834764831845f
#define THR 8.0f

__device__ __forceinline__ u16 f2bf(float x) {
  union { float f; uint32_t u; } v; v.f = x;
  uint32_t r = v.u + 0x7FFFu + ((v.u >> 16) & 1u);
  return (u16)(r >> 16);
}

__device__ __forceinline__ void load_lds16(const void* g, void* l) {
  __builtin_amdgcn_global_load_lds(
      (const __attribute__((address_space(1))) void*)g,
      (__attribute__((address_space(3))) void*)l, 16, 0, 0);
}

#define MFMA16(a, b, c) __builtin_amdgcn_mfma_f32_16x16x32_bf16((a), (b), (c), 0, 0, 0)

// ---------------- fp32 -> bf16 convert (x) ----------------
__global__ __launch_bounds__(256) void k_cvt(const float* __restrict__ in,
                                             u16* __restrict__ out, int n4) {
  int i = blockIdx.x * 256 + threadIdx.x;
  if (i >= n4) return;
  float4 v = ((const float4*)in)[i];
  ushort4 o;
  o.x = f2bf(v.x); o.y = f2bf(v.y); o.z = f2bf(v.z); o.w = f2bf(v.w);
  ((ushort4*)out)[i] = o;
}

// ---------------- fused 4-weight fp32 -> bf16 convert ----------------
__global__ __launch_bounds__(256) void k_cvt_w(const float* __restrict__ w0, const float* __restrict__ w1,
                                               const float* __restrict__ w2, const float* __restrict__ w3,
                                               u16* __restrict__ o0, u16* __restrict__ o1,
                                               u16* __restrict__ o2, u16* __restrict__ o3, int n4each) {
  int i = blockIdx.x * 256 + threadIdx.x;
  int seg = i / n4each, off = i - seg * n4each;
  const float* in = seg == 0 ? w0 : seg == 1 ? w1 : seg == 2 ? w2 : w3;
  u16* out = seg == 0 ? o0 : seg == 1 ? o1 : seg == 2 ? o2 : o3;
  float4 v = ((const float4*)in)[off];
  ushort4 o;
  o.x = f2bf(v.x); o.y = f2bf(v.y); o.z = f2bf(v.z); o.w = f2bf(v.w);
  ((ushort4*)out)[off] = o;
}

// ---------------- shared GEMM K-loop body (m97 pattern) ----------------
// Computes acc[4][4] for the 128x128 tile at (m0, n0) of A[M][2048] x B[n][2048]^T.
__device__ __forceinline__ void gemm_body(const u16* __restrict__ A, const u16* __restrict__ B,
                                          int m0, int n0, int t, f32x4 (*acc)[4],
                                          u16* lA, u16* lB) {
  const int lane = t & 63, w = t >> 6, lo = lane & 15, g = lane >> 4;
  const int wr = w >> 1, wc = w & 1;
  const u16* ga = A + (size_t)(m0 + (t >> 2)) * D_DIM + (t & 3) * 8;
  const u16* gb = B + (size_t)(n0 + (t >> 2)) * D_DIM + (t & 3) * 8;
  for (int k0 = 0; k0 < D_DIM; k0 += 32) {
    load_lds16(ga + k0, &lA[t * 8]);
    load_lds16(ga + (size_t)64 * D_DIM + k0, &lA[2048 + t * 8]);
    load_lds16(gb + k0, &lB[t * 8]);
    load_lds16(gb + (size_t)64 * D_DIM + k0, &lB[2048 + t * 8]);
    __syncthreads();
    short8 af[4], bfr[4];
#pragma unroll
    for (int m = 0; m < 4; ++m)
      af[m] = *(const short8*)&lA[(wr * 64 + m * 16 + lo) * 32 + g * 8];
#pragma unroll
    for (int n = 0; n < 4; ++n)
      bfr[n] = *(const short8*)&lB[(wc * 64 + n * 16 + lo) * 32 + g * 8];
#pragma unroll
    for (int m = 0; m < 4; ++m)
#pragma unroll
      for (int n = 0; n < 4; ++n) acc[m][n] = MFMA16(af[m], bfr[n], acc[m][n]);
    __syncthreads();
  }
}

// ---------------- fused QKV GEMM: 1D grid 1152, XCD-swizzled, col-major chunks ----------------
__global__ __launch_bounds__(256) void k_gemm_qkv(const u16* __restrict__ A,
                                                  const u16* __restrict__ Bq, const u16* __restrict__ Bk,
                                                  const u16* __restrict__ Bv,
                                                  const float* __restrict__ bq, const float* __restrict__ bk,
                                                  const float* __restrict__ bv,
                                                  float* __restrict__ Q0, float* __restrict__ K0,
                                                  u16* __restrict__ Vb) {
  __shared__ u16 lA[128 * 32];
  __shared__ u16 lB[128 * 32];
  const int id = blockIdx.x;
  const int swz = (id & 7) * 144 + (id >> 3);   // 1152/8 = 144 tiles per XCD
  const int bx = swz / 24, by = swz % 24;       // col-major chunks: B-panels stay L2-hot
  const int n0g = bx * 128, m0 = by * 128;
  const int seg = n0g >> 11, n0 = n0g & 2047;
  const u16* B = seg == 0 ? Bq : seg == 1 ? Bk : Bv;
  const float* bias = seg == 0 ? bq : seg == 1 ? bk : bv;
  const int t = threadIdx.x;
  const int lane = t & 63, w = t >> 6, lo = lane & 15, g = lane >> 4;
  const int wr = w >> 1, wc = w & 1;
  const f32x4 zero4 = {0.f, 0.f, 0.f, 0.f};
  f32x4 acc[4][4];
#pragma unroll
  for (int m = 0; m < 4; ++m)
#pragma unroll
    for (int n = 0; n < 4; ++n) acc[m][n] = zero4;
  gemm_body(A, B, m0, n0, t, acc, lA, lB);
#pragma unroll
  for (int m = 0; m < 4; ++m) {
    const int row = m0 + wr * 64 + m * 16 + 4 * g;
#pragma unroll
    for (int n = 0; n < 4; ++n) {
      const int col = n0 + wc * 64 + n * 16 + lo;
      const float bb = bias[col];
#pragma unroll
      for (int r = 0; r < 4; ++r) {
        const float val = acc[m][n][r] + bb;
        if (seg == 2)
          Vb[(size_t)(row + r) * 2048 + col] = f2bf(val);
        else if (seg == 1)
          K0[(size_t)(row + r) * 2048 + col] = val;
        else
          Q0[(size_t)(row + r) * 2048 + col] = val;
      }
    }
  }
}

// ---------------- generic NT GEMM (used for WO), 1D grid, XCD-swizzled ----------------
template <bool BF16OUT>
__global__ __launch_bounds__(256) void k_gemm_nt(const u16* __restrict__ A,
                                                 const u16* __restrict__ B,
                                                 const float* __restrict__ bias,
                                                 void* __restrict__ Cv, int nby) {
  __shared__ u16 lA[128 * 32];
  __shared__ u16 lB[128 * 32];
  const int id = blockIdx.x;
  const int cpx = gridDim.x >> 3;
  const int swz = (id & 7) * cpx + (id >> 3);
  const int bx = swz / nby, by = swz % nby;
  const int n0 = bx * 128, m0 = by * 128;
  const int t = threadIdx.x;
  const int lane = t & 63, w = t >> 6, lo = lane & 15, g = lane >> 4;
  const int wr = w >> 1, wc = w & 1;
  const f32x4 zero4 = {0.f, 0.f, 0.f, 0.f};
  f32x4 acc[4][4];
#pragma unroll
  for (int m = 0; m < 4; ++m)
#pragma unroll
    for (int n = 0; n < 4; ++n) acc[m][n] = zero4;
  gemm_body(A, B, m0, n0, t, acc, lA, lB);
#pragma unroll
  for (int m = 0; m < 4; ++m) {
    const int row = m0 + wr * 64 + m * 16 + 4 * g;
#pragma unroll
    for (int n = 0; n < 4; ++n) {
      const int col = n0 + wc * 64 + n * 16 + lo;
      const float bb = bias[col];
#pragma unroll
      for (int r = 0; r < 4; ++r) {
        const float val = acc[m][n][r] + bb;
        if (BF16OUT)
          ((u16*)Cv)[(size_t)(row + r) * 2048 + col] = f2bf(val);
        else
          ((float*)Cv)[(size_t)(row + r) * 2048 + col] = val;
      }
    }
  }
}

// ---------------- fused RMSNorm (bias pre-added) + RoPE -> bf16 ----------------
__global__ __launch_bounds__(256) void k_rms_rope(const float* __restrict__ H,
                                                  const float* __restrict__ gain,
                                                  const float* __restrict__ cosT,
                                                  const float* __restrict__ sinT,
                                                  u16* __restrict__ out) {
  const int s = blockIdx.x, t = threadIdx.x;
  const float* hp = H + (size_t)s * D_DIM + t * 8;
  float4 v0 = *(const float4*)hp;
  float4 v1 = *(const float4*)(hp + 4);
  float h[8] = {v0.x, v0.y, v0.z, v0.w, v1.x, v1.y, v1.z, v1.w};
  float ss = 0.f;
#pragma unroll
  for (int j = 0; j < 8; ++j) ss += h[j] * h[j];
#pragma unroll
  for (int off = 32; off > 0; off >>= 1) ss += __shfl_xor(ss, off);
  __shared__ float red[4];
  if ((t & 63) == 0) red[t >> 6] = ss;
  __syncthreads();
  ss = red[0] + red[1] + red[2] + red[3];
  const float rs = rsqrtf(ss * (1.f / D_DIM) + 1e-6f);
  const float4 g0 = *(const float4*)(gain + t * 8);
  const float4 g1 = *(const float4*)(gain + t * 8 + 4);
  float y[8];
  y[0] = h[0] * rs * g0.x; y[1] = h[1] * rs * g0.y;
  y[2] = h[2] * rs * g0.z; y[3] = h[3] * rs * g0.w;
  y[4] = h[4] * rs * g1.x; y[5] = h[5] * rs * g1.y;
  y[6] = h[6] * rs * g1.z; y[7] = h[7] * rs * g1.w;
  const int cbase = ((t * 8) & 127) >> 1;
  short8 o8;
#pragma unroll
  for (int i = 0; i < 4; ++i) {
    const float cs = cosT[s * 64 + cbase + i];
    const float sn = sinT[s * 64 + cbase + i];
    const float yr = y[2 * i] * cs - y[2 * i + 1] * sn;
    const float yi = y[2 * i] * sn + y[2 * i + 1] * cs;
    o8[2 * i] = (short)f2bf(yr);
    o8[2 * i + 1] = (short)f2bf(yi);
  }
  *(short8*)(out + (size_t)s * D_DIM + t * 8) = o8;
}

// ---------------- bf16 transpose [S][D] -> [D][S] (64x64 tiles) ----------------
__global__ __launch_bounds__(256) void k_transpose(const u16* __restrict__ in,
                                                   u16* __restrict__ out) {
  __shared__ u16 tile[64][72];
  const int s0 = blockIdx.x * 64, d0 = blockIdx.y * 64;
  const int t = threadIdx.x;
  const int r = t >> 3, c8 = (t & 7) * 8;
#pragma unroll
  for (int p = 0; p < 2; ++p) {
    short8 v = *(const short8*)&in[(size_t)(s0 + r + p * 32) * D_DIM + d0 + c8];
#pragma unroll
    for (int j = 0; j < 8; ++j) tile[r + p * 32][c8 + j] = (u16)v[j];
  }
  __syncthreads();
#pragma unroll
  for (int p = 0; p < 2; ++p) {
    const int dr = r + p * 32;
    short8 o;
#pragma unroll
    for (int j = 0; j < 8; ++j) o[j] = (short)tile[c8 + j][dr];
    *(short8*)&out[(size_t)(d0 + dr) * S_LEN + s0 + c8] = o;
  }
}

// ---------------- banded flash attention, window-split 8-wave blocks ----------------
// grid (S/64, H), 512 threads. Waves 0-3: lower half of KV window for rows
// [q0+wr*16, +16); waves 4-7: upper half for the same rows. LDS combine.
// KVBLK = 64. Defer-max THR=8. Interior fast path (<=2 boundary iters/window).
__global__ __launch_bounds__(512) void k_attn2(const u16* __restrict__ Q,
                                               const u16* __restrict__ Kmat,
                                               const u16* __restrict__ Vt,
                                               u16* __restrict__ Om) {
  const int qt = blockIdx.x, h = blockIdx.y;
  const int t = threadIdx.x;
  const int w = t >> 6, wr = w & 3, half = w >> 2;
  const int lane = t & 63, lo = lane & 15, g = lane >> 4;
  const int q0 = qt * 64;
  const int qbase = q0 + wr * 16;
  const size_t hoff = (size_t)h * 128;

  __shared__ u16 ldsp[8][16][72];      // P tiles, padded: 2-way banks only
  __shared__ float cmbO[4][16][132];   // combine buffer, padded
  __shared__ float cmbM[4][16];
  __shared__ float cmbL[4][16];

  short8 qf[4];
  const u16* qp = Q + (size_t)(qbase + lo) * D_DIM + hoff + g * 8;
#pragma unroll
  for (int c = 0; c < 4; ++c) qf[c] = *(const short8*)(qp + c * 32);

  const f32x4 zero4 = {0.f, 0.f, 0.f, 0.f};
  f32x4 oacc[8];
#pragma unroll
  for (int ct = 0; ct < 8; ++ct) oacc[ct] = zero4;
  float mrun[4] = {-1e30f, -1e30f, -1e30f, -1e30f};
  float lrun[4] = {0.f, 0.f, 0.f, 0.f};

  int jlo = q0 - WIN; if (jlo < 0) jlo = 0;
  int jhi = q0 + 63 + WIN + 1; if (jhi > S_LEN) jhi = S_LEN;
  const int NT = (jhi - jlo) >> 6;  // window is always a multiple of 64
  const int it0 = half ? (NT >> 1) : 0;
  const int it1 = half ? NT : (NT >> 1);

  for (int it = it0; it < it1; ++it) {
    const int j0 = jlo + (it << 6);
    // ---- QK^T (16 MFMAs) ----
    f32x4 sc[4];
    const u16* kp = Kmat + (size_t)(j0 + lo) * D_DIM + hoff + g * 8;
#pragma unroll
    for (int jt = 0; jt < 4; ++jt) {
      f32x4 s = zero4;
      const u16* kpj = kp + (size_t)(jt * 16) * D_DIM;
#pragma unroll
      for (int c = 0; c < 4; ++c) {
        short8 kf = *(const short8*)(kpj + c * 32);
        s = MFMA16(qf[c], kf, s);
      }
      sc[jt] = s;
    }
    // ---- softmax ----
    const int dq = j0 - q0;  // wave-uniform
    const bool interior = (dq >= -704) && (dq <= 704);
    float alpha[4];
    bool need = false;
#pragma unroll
    for (int r = 0; r < 4; ++r) {
      float a0, a1, a2, a3;
      if (interior) {
        a0 = sc[0][r] * INV_SQRT_HD; a1 = sc[1][r] * INV_SQRT_HD;
        a2 = sc[2][r] * INV_SQRT_HD; a3 = sc[3][r] * INV_SQRT_HD;
      } else {
        const int dk = j0 + lo - (qbase + 4 * g + r);  // delta for jt=0
        a0 = (dk >= -WIN && dk <= WIN) ? sc[0][r] * INV_SQRT_HD : -3e38f;
        a1 = (dk + 16 >= -WIN && dk + 16 <= WIN) ? sc[1][r] * INV_SQRT_HD : -3e38f;
        a2 = (dk + 32 >= -WIN && dk + 32 <= WIN) ? sc[2][r] * INV_SQRT_HD : -3e38f;
        a3 = (dk + 48 >= -WIN && dk + 48 <= WIN) ? sc[3][r] * INV_SQRT_HD : -3e38f;
      }
      float mx = fmaxf(fmaxf(a0, a1), fmaxf(a2, a3));
#pragma unroll
      for (int off = 8; off > 0; off >>= 1) mx = fmaxf(mx, __shfl_xor(mx, off));
      const float mn = (mx > mrun[r] + THR) ? mx : mrun[r];  // defer-max
      alpha[r] = __expf(mrun[r] - mn);
      need |= (mn != mrun[r]);
      const float p0 = __expf(a0 - mn), p1 = __expf(a1 - mn);
      const float p2 = __expf(a2 - mn), p3 = __expf(a3 - mn);
      float rsum = (p0 + p1) + (p2 + p3);
#pragma unroll
      for (int off = 8; off > 0; off >>= 1) rsum += __shfl_xor(rsum, off);
      lrun[r] = lrun[r] * alpha[r] + rsum;
      mrun[r] = mn;
      const int pr = 4 * g + r;
      ldsp[w][pr][lo]      = f2bf(p0);
      ldsp[w][pr][16 + lo] = f2bf(p1);
      ldsp[w][pr][32 + lo] = f2bf(p2);
      ldsp[w][pr][48 + lo] = f2bf(p3);
    }
    if (__any(need)) {
      const f32x4 av = {alpha[0], alpha[1], alpha[2], alpha[3]};
#pragma unroll
      for (int ct = 0; ct < 8; ++ct) oacc[ct] *= av;
    }
    // ---- PV (16 MFMAs) ----
    const short8 pf0 = *(const short8*)&ldsp[w][lo][g * 8];
    const short8 pf1 = *(const short8*)&ldsp[w][lo][32 + g * 8];
    const u16* vp = Vt + (hoff + lo) * S_LEN + j0 + g * 8;
#pragma unroll
    for (int ct = 0; ct < 8; ++ct) {
      const u16* vpc = vp + (size_t)ct * 16 * S_LEN;
      short8 vf0 = *(const short8*)(vpc);
      short8 vf1 = *(const short8*)(vpc + 32);
      oacc[ct] = MFMA16(pf0, vf0, oacc[ct]);
      oacc[ct] = MFMA16(pf1, vf1, oacc[ct]);
    }
  }

  // ---- combine halves ----
  if (half == 1) {
#pragma unroll
    for (int ct = 0; ct < 8; ++ct)
#pragma unroll
      for (int r = 0; r < 4; ++r) cmbO[wr][4 * g + r][ct * 16 + lo] = oacc[ct][r];
    if (lo == 0) {
#pragma unroll
      for (int r = 0; r < 4; ++r) { cmbM[wr][4 * g + r] = mrun[r]; cmbL[wr][4 * g + r] = lrun[r]; }
    }
  }
  __syncthreads();
  if (half == 0) {
    float sa[4], sb[4], inv[4];
#pragma unroll
    for (int r = 0; r < 4; ++r) {
      const float mb = cmbM[wr][4 * g + r], lb = cmbL[wr][4 * g + r];
      const float mn = fmaxf(mrun[r], mb);
      sa[r] = __expf(mrun[r] - mn);
      sb[r] = __expf(mb - mn);
      inv[r] = 1.f / (lrun[r] * sa[r] + lb * sb[r]);
    }
#pragma unroll
    for (int ct = 0; ct < 8; ++ct)
#pragma unroll
      for (int r = 0; r < 4; ++r) {
        const float o = (oacc[ct][r] * sa[r] + cmbO[wr][4 * g + r][ct * 16 + lo] * sb[r]) * inv[r];
        Om[(size_t)(qbase + 4 * g + r) * D_DIM + hoff + ct * 16 + lo] = f2bf(o);
      }
  }
}

extern "C" void kernel_launch(void* const* d_in, const int* in_sizes, int n_in,
                              void* d_out, int out_size, void* d_ws, size_t ws_size,
                              hipStream_t stream) {
  const float* x    = (const float*)d_in[0];
  const float* wq   = (const float*)d_in[1];
  const float* bq   = (const float*)d_in[2];
  const float* wk   = (const float*)d_in[3];
  const float* bk   = (const float*)d_in[4];
  const float* wv   = (const float*)d_in[5];
  const float* bv   = (const float*)d_in[6];
  const float* wo   = (const float*)d_in[7];
  const float* bo   = (const float*)d_in[8];
  const float* gq   = (const float*)d_in[9];
  const float* gk   = (const float*)d_in[10];
  const float* cosT = (const float*)d_in[11];
  const float* sinT = (const float*)d_in[12];

  char* ws = (char*)d_ws;
  const size_t WB = (size_t)D_DIM * D_DIM * 2;  // bf16 weight: 8.4 MB
  const size_t XB = (size_t)S_LEN * D_DIM * 2;  // bf16 activation: 12.6 MB
  const size_t XF = (size_t)S_LEN * D_DIM * 4;  // fp32 activation: 25.2 MB
  u16*   wq_bf = (u16*)(ws);
  u16*   wk_bf = (u16*)(ws + WB);
  u16*   wv_bf = (u16*)(ws + 2 * WB);
  u16*   wo_bf = (u16*)(ws + 3 * WB);
  u16*   x_bf  = (u16*)(ws + 4 * WB);
  float* Q0    = (float*)(ws + 4 * WB + XB);
  float* K0    = (float*)(ws + 4 * WB + XB + XF);
  u16*   V0b   = (u16*)(ws + 4 * WB + XB + 2 * XF);
  // stream-ordered reuse:
  u16* q_bf = x_bf;        // x_bf dead after QKV GEMM
  u16* k_bf = wq_bf;       // wq/wk bf16 dead after QKV GEMM
  u16* vT   = (u16*)Q0;    // Q0 dead after rms_rope(Q)
  u16* attn = (u16*)K0;    // K0 dead after rms_rope(K)

  const int nw4 = (D_DIM * D_DIM) / 4;
  const int nx4 = (S_LEN * D_DIM) / 4;
  k_cvt<<<nx4 / 256, 256, 0, stream>>>(x, x_bf, nx4);
  k_cvt_w<<<4 * nw4 / 256, 256, 0, stream>>>(wq, wk, wv, wo, wq_bf, wk_bf, wv_bf, wo_bf, nw4);

  k_gemm_qkv<<<1152, 256, 0, stream>>>(x_bf, wq_bf, wk_bf, wv_bf, bq, bk, bv, Q0, K0, V0b);

  k_rms_rope<<<S_LEN, 256, 0, stream>>>(Q0, gq, cosT, sinT, q_bf);
  k_rms_rope<<<S_LEN, 256, 0, stream>>>(K0, gk, cosT, sinT, k_bf);
  k_transpose<<<dim3(S_LEN / 64, D_DIM / 64), 256, 0, stream>>>(V0b, vT);

  k_attn2<<<dim3(S_LEN / 64, 16), 512, 0, stream>>>(q_bf, k_bf, vT, attn);

  k_gemm_nt<false><<<384, 256, 0, stream>>>(attn, wo_bf, bo, (float*)d_out, 24);
}

// Round 6
// 337.888 us; speedup vs baseline: 1.6036x; 1.6036x over previous
//
#include <hip/hip_runtime.h>
#include <stdint.h>

typedef unsigned short u16;
typedef __attribute__((ext_vector_type(8))) short short8;
typedef __attribute__((ext_vector_type(4))) float f32x4;

#define S_LEN 3072
#define D_DIM 2048
#define WIN 768
#define INV_SQRT_HD 0.08838834764831845f
#define THR 8.0f

__device__ __forceinline__ u16 f2bf(float x) {
  union { float f; uint32_t u; } v; v.f = x;
  uint32_t r = v.u + 0x7FFFu + ((v.u >> 16) & 1u);
  return (u16)(r >> 16);
}

__device__ __forceinline__ void load_lds16(const void* g, void* l) {
  __builtin_amdgcn_global_load_lds(
      (const __attribute__((address_space(1))) void*)g,
      (__attribute__((address_space(3))) void*)l, 16, 0, 0);
}

#define MFMA16(a, b, c) __builtin_amdgcn_mfma_f32_16x16x32_bf16((a), (b), (c), 0, 0, 0)

// ---------------- fp32 -> bf16 convert (x) ----------------
__global__ __launch_bounds__(256) void k_cvt(const float* __restrict__ in,
                                             u16* __restrict__ out, int n4) {
  int i = blockIdx.x * 256 + threadIdx.x;
  if (i >= n4) return;
  float4 v = ((const float4*)in)[i];
  ushort4 o;
  o.x = f2bf(v.x); o.y = f2bf(v.y); o.z = f2bf(v.z); o.w = f2bf(v.w);
  ((ushort4*)out)[i] = o;
}

// ---------------- fused 4-weight fp32 -> bf16 convert ----------------
__global__ __launch_bounds__(256) void k_cvt_w(const float* __restrict__ w0, const float* __restrict__ w1,
                                               const float* __restrict__ w2, const float* __restrict__ w3,
                                               u16* __restrict__ o0, u16* __restrict__ o1,
                                               u16* __restrict__ o2, u16* __restrict__ o3, int n4each) {
  int i = blockIdx.x * 256 + threadIdx.x;
  int seg = i / n4each, off = i - seg * n4each;
  const float* in = seg == 0 ? w0 : seg == 1 ? w1 : seg == 2 ? w2 : w3;
  u16* out = seg == 0 ? o0 : seg == 1 ? o1 : seg == 2 ? o2 : o3;
  float4 v = ((const float4*)in)[off];
  ushort4 o;
  o.x = f2bf(v.x); o.y = f2bf(v.y); o.z = f2bf(v.z); o.w = f2bf(v.w);
  ((ushort4*)out)[off] = o;
}

// ---------------- shared GEMM K-loop body (m97 pattern) ----------------
__device__ __forceinline__ void gemm_body(const u16* __restrict__ A, const u16* __restrict__ B,
                                          int m0, int n0, int t, f32x4 (*acc)[4],
                                          u16* lA, u16* lB) {
  const int lane = t & 63, w = t >> 6, lo = lane & 15, g = lane >> 4;
  const int wr = w >> 1, wc = w & 1;
  const u16* ga = A + (size_t)(m0 + (t >> 2)) * D_DIM + (t & 3) * 8;
  const u16* gb = B + (size_t)(n0 + (t >> 2)) * D_DIM + (t & 3) * 8;
  for (int k0 = 0; k0 < D_DIM; k0 += 32) {
    load_lds16(ga + k0, &lA[t * 8]);
    load_lds16(ga + (size_t)64 * D_DIM + k0, &lA[2048 + t * 8]);
    load_lds16(gb + k0, &lB[t * 8]);
    load_lds16(gb + (size_t)64 * D_DIM + k0, &lB[2048 + t * 8]);
    __syncthreads();
    short8 af[4], bfr[4];
#pragma unroll
    for (int m = 0; m < 4; ++m)
      af[m] = *(const short8*)&lA[(wr * 64 + m * 16 + lo) * 32 + g * 8];
#pragma unroll
    for (int n = 0; n < 4; ++n)
      bfr[n] = *(const short8*)&lB[(wc * 64 + n * 16 + lo) * 32 + g * 8];
#pragma unroll
    for (int m = 0; m < 4; ++m)
#pragma unroll
      for (int n = 0; n < 4; ++n) acc[m][n] = MFMA16(af[m], bfr[n], acc[m][n]);
    __syncthreads();
  }
}

// ---------------- fused QKV GEMM: 1D grid 1152, XCD-swizzled, col-major chunks ----------------
__global__ __launch_bounds__(256) void k_gemm_qkv(const u16* __restrict__ A,
                                                  const u16* __restrict__ Bq, const u16* __restrict__ Bk,
                                                  const u16* __restrict__ Bv,
                                                  const float* __restrict__ bq, const float* __restrict__ bk,
                                                  const float* __restrict__ bv,
                                                  float* __restrict__ Q0, float* __restrict__ K0,
                                                  u16* __restrict__ Vb) {
  __shared__ u16 lA[128 * 32];
  __shared__ u16 lB[128 * 32];
  const int id = blockIdx.x;
  const int swz = (id & 7) * 144 + (id >> 3);
  const int bx = swz / 24, by = swz % 24;
  const int n0g = bx * 128, m0 = by * 128;
  const int seg = n0g >> 11, n0 = n0g & 2047;
  const u16* B = seg == 0 ? Bq : seg == 1 ? Bk : Bv;
  const float* bias = seg == 0 ? bq : seg == 1 ? bk : bv;
  const int t = threadIdx.x;
  const int lane = t & 63, w = t >> 6, lo = lane & 15, g = lane >> 4;
  const int wr = w >> 1, wc = w & 1;
  const f32x4 zero4 = {0.f, 0.f, 0.f, 0.f};
  f32x4 acc[4][4];
#pragma unroll
  for (int m = 0; m < 4; ++m)
#pragma unroll
    for (int n = 0; n < 4; ++n) acc[m][n] = zero4;
  gemm_body(A, B, m0, n0, t, acc, lA, lB);
#pragma unroll
  for (int m = 0; m < 4; ++m) {
    const int row = m0 + wr * 64 + m * 16 + 4 * g;
#pragma unroll
    for (int n = 0; n < 4; ++n) {
      const int col = n0 + wc * 64 + n * 16 + lo;
      const float bb = bias[col];
#pragma unroll
      for (int r = 0; r < 4; ++r) {
        const float val = acc[m][n][r] + bb;
        if (seg == 2)
          Vb[(size_t)(row + r) * 2048 + col] = f2bf(val);
        else if (seg == 1)
          K0[(size_t)(row + r) * 2048 + col] = val;
        else
          Q0[(size_t)(row + r) * 2048 + col] = val;
      }
    }
  }
}

// ---------------- generic NT GEMM (WO), 1D grid, XCD-swizzled ----------------
template <bool BF16OUT>
__global__ __launch_bounds__(256) void k_gemm_nt(const u16* __restrict__ A,
                                                 const u16* __restrict__ B,
                                                 const float* __restrict__ bias,
                                                 void* __restrict__ Cv, int nby) {
  __shared__ u16 lA[128 * 32];
  __shared__ u16 lB[128 * 32];
  const int id = blockIdx.x;
  const int cpx = gridDim.x >> 3;
  const int swz = (id & 7) * cpx + (id >> 3);
  const int bx = swz / nby, by = swz % nby;
  const int n0 = bx * 128, m0 = by * 128;
  const int t = threadIdx.x;
  const int lane = t & 63, w = t >> 6, lo = lane & 15, g = lane >> 4;
  const int wr = w >> 1, wc = w & 1;
  const f32x4 zero4 = {0.f, 0.f, 0.f, 0.f};
  f32x4 acc[4][4];
#pragma unroll
  for (int m = 0; m < 4; ++m)
#pragma unroll
    for (int n = 0; n < 4; ++n) acc[m][n] = zero4;
  gemm_body(A, B, m0, n0, t, acc, lA, lB);
#pragma unroll
  for (int m = 0; m < 4; ++m) {
    const int row = m0 + wr * 64 + m * 16 + 4 * g;
#pragma unroll
    for (int n = 0; n < 4; ++n) {
      const int col = n0 + wc * 64 + n * 16 + lo;
      const float bb = bias[col];
#pragma unroll
      for (int r = 0; r < 4; ++r) {
        const float val = acc[m][n][r] + bb;
        if (BF16OUT)
          ((u16*)Cv)[(size_t)(row + r) * 2048 + col] = f2bf(val);
        else
          ((float*)Cv)[(size_t)(row + r) * 2048 + col] = val;
      }
    }
  }
}

// ---------------- fused RMSNorm (bias pre-added) + RoPE -> bf16 ----------------
__global__ __launch_bounds__(256) void k_rms_rope(const float* __restrict__ H,
                                                  const float* __restrict__ gain,
                                                  const float* __restrict__ cosT,
                                                  const float* __restrict__ sinT,
                                                  u16* __restrict__ out) {
  const int s = blockIdx.x, t = threadIdx.x;
  const float* hp = H + (size_t)s * D_DIM + t * 8;
  float4 v0 = *(const float4*)hp;
  float4 v1 = *(const float4*)(hp + 4);
  float h[8] = {v0.x, v0.y, v0.z, v0.w, v1.x, v1.y, v1.z, v1.w};
  float ss = 0.f;
#pragma unroll
  for (int j = 0; j < 8; ++j) ss += h[j] * h[j];
#pragma unroll
  for (int off = 32; off > 0; off >>= 1) ss += __shfl_xor(ss, off);
  __shared__ float red[4];
  if ((t & 63) == 0) red[t >> 6] = ss;
  __syncthreads();
  ss = red[0] + red[1] + red[2] + red[3];
  const float rs = rsqrtf(ss * (1.f / D_DIM) + 1e-6f);
  const float4 g0 = *(const float4*)(gain + t * 8);
  const float4 g1 = *(const float4*)(gain + t * 8 + 4);
  float y[8];
  y[0] = h[0] * rs * g0.x; y[1] = h[1] * rs * g0.y;
  y[2] = h[2] * rs * g0.z; y[3] = h[3] * rs * g0.w;
  y[4] = h[4] * rs * g1.x; y[5] = h[5] * rs * g1.y;
  y[6] = h[6] * rs * g1.z; y[7] = h[7] * rs * g1.w;
  const int cbase = ((t * 8) & 127) >> 1;
  short8 o8;
#pragma unroll
  for (int i = 0; i < 4; ++i) {
    const float cs = cosT[s * 64 + cbase + i];
    const float sn = sinT[s * 64 + cbase + i];
    const float yr = y[2 * i] * cs - y[2 * i + 1] * sn;
    const float yi = y[2 * i] * sn + y[2 * i + 1] * cs;
    o8[2 * i] = (short)f2bf(yr);
    o8[2 * i + 1] = (short)f2bf(yi);
  }
  *(short8*)(out + (size_t)s * D_DIM + t * 8) = o8;
}

// ---------------- bf16 transpose [S][D] -> [D][S] (64x64 tiles) ----------------
__global__ __launch_bounds__(256) void k_transpose(const u16* __restrict__ in,
                                                   u16* __restrict__ out) {
  __shared__ u16 tile[64][72];
  const int s0 = blockIdx.x * 64, d0 = blockIdx.y * 64;
  const int t = threadIdx.x;
  const int r = t >> 3, c8 = (t & 7) * 8;
#pragma unroll
  for (int p = 0; p < 2; ++p) {
    short8 v = *(const short8*)&in[(size_t)(s0 + r + p * 32) * D_DIM + d0 + c8];
#pragma unroll
    for (int j = 0; j < 8; ++j) tile[r + p * 32][c8 + j] = (u16)v[j];
  }
  __syncthreads();
#pragma unroll
  for (int p = 0; p < 2; ++p) {
    const int dr = r + p * 32;
    short8 o;
#pragma unroll
    for (int j = 0; j < 8; ++j) o[j] = (short)tile[c8 + j][dr];
    *(short8*)&out[(size_t)(d0 + dr) * S_LEN + s0 + c8] = o;
  }
}

// ---------------- banded flash attention with cooperative LDS staging ----------------
// grid (S/64, H), 4 waves; wave owns 16 q-rows. KVBLK=32. K,Vt tiles staged via
// global_load_lds with XOR chunk-swizzle (pre-swizzled source, linear dest,
// swizzled ds_read). Defer-max THR=8, wave-uniform interior fast path.
__global__ __launch_bounds__(256) void k_attn3(const u16* __restrict__ Q,
                                               const u16* __restrict__ Kmat,
                                               const u16* __restrict__ Vt,
                                               u16* __restrict__ Om) {
  const int qt = blockIdx.x, h = blockIdx.y;
  const int t = threadIdx.x, w = t >> 6, lane = t & 63, lo = lane & 15, g = lane >> 4;
  const int q0 = qt * 64;
  const int qbase = q0 + w * 16;
  const size_t hoff = (size_t)h * 128;

  __shared__ u16 lK[32 * 128];       // [j 0..31][128 d] 256B rows, 16 chunks, swz (row&7)
  __shared__ u16 lV[128 * 32];       // [d 0..127][32 j]  64B rows,  4 chunks, swz (row&3)
  __shared__ u16 ldsp[4][16][40];    // P tiles, padded to 80B rows (conflict-free)

  short8 qf[4];
  const u16* qp = Q + (size_t)(qbase + lo) * D_DIM + hoff + g * 8;
#pragma unroll
  for (int c = 0; c < 4; ++c) qf[c] = *(const short8*)(qp + c * 32);

  const f32x4 zero4 = {0.f, 0.f, 0.f, 0.f};
  f32x4 oacc[8];
#pragma unroll
  for (int ct = 0; ct < 8; ++ct) oacc[ct] = zero4;
  float mrun[4] = {-1e30f, -1e30f, -1e30f, -1e30f};
  float lrun[4] = {0.f, 0.f, 0.f, 0.f};

  int jlo = q0 - WIN; if (jlo < 0) jlo = 0;
  int jhi = q0 + 63 + WIN + 1; if (jhi > S_LEN) jhi = S_LEN;

  // staging indices (constant per thread)
  const int krow0 = t >> 4, kch0 = t & 15;          // e = t
  const int krow1 = (t + 256) >> 4, kch1 = t & 15;  // e = t+256
  const int vrow0 = t >> 2, vch0 = t & 3;
  const int vrow1 = (t + 256) >> 2, vch1 = t & 3;

  for (int j0 = jlo; j0 < jhi; j0 += 32) {
    __syncthreads();  // previous iteration's LDS reads complete
    // ---- cooperative stage: K tile (8KB) + Vt tile (8KB), pre-swizzled source ----
    load_lds16(Kmat + (size_t)(j0 + krow0) * D_DIM + hoff + ((kch0 ^ (krow0 & 7)) << 3),
               &lK[t * 8]);
    load_lds16(Kmat + (size_t)(j0 + krow1) * D_DIM + hoff + ((kch1 ^ (krow1 & 7)) << 3),
               &lK[(t + 256) * 8]);
    load_lds16(Vt + (size_t)(hoff + vrow0) * S_LEN + j0 + ((vch0 ^ (vrow0 & 3)) << 3),
               &lV[t * 8]);
    load_lds16(Vt + (size_t)(hoff + vrow1) * S_LEN + j0 + ((vch1 ^ (vrow1 & 3)) << 3),
               &lV[(t + 256) * 8]);
    __syncthreads();  // vmcnt drained before barrier -> tiles visible

    // ---- QK^T from LDS (8 MFMAs) ----
    f32x4 sc0 = zero4, sc1 = zero4;
#pragma unroll
    for (int c = 0; c < 4; ++c) {
      const short8 kf0 = *(const short8*)&lK[(lo)*128 + (((g + 4 * c) ^ (lo & 7)) << 3)];
      const short8 kf1 = *(const short8*)&lK[(16 + lo) * 128 + (((g + 4 * c) ^ (lo & 7)) << 3)];
      sc0 = MFMA16(qf[c], kf0, sc0);
      sc1 = MFMA16(qf[c], kf1, sc1);
    }

    // ---- softmax (defer-max, interior fast path) ----
    const int dq = j0 - q0;
    const bool interior = (dq >= -704) && (dq <= 736);
    float alpha[4];
    bool need = false;
#pragma unroll
    for (int r = 0; r < 4; ++r) {
      float a0, a1;
      if (interior) {
        a0 = sc0[r] * INV_SQRT_HD;
        a1 = sc1[r] * INV_SQRT_HD;
      } else {
        const int dk = j0 + lo - (qbase + 4 * g + r);
        a0 = (dk >= -WIN && dk <= WIN) ? sc0[r] * INV_SQRT_HD : -3e38f;
        a1 = (dk + 16 >= -WIN && dk + 16 <= WIN) ? sc1[r] * INV_SQRT_HD : -3e38f;
      }
      float mx = fmaxf(a0, a1);
#pragma unroll
      for (int off = 8; off > 0; off >>= 1) mx = fmaxf(mx, __shfl_xor(mx, off));
      const float mn = (mx > mrun[r] + THR) ? mx : mrun[r];
      alpha[r] = __expf(mrun[r] - mn);
      need |= (mn != mrun[r]);
      const float p0 = __expf(a0 - mn);
      const float p1 = __expf(a1 - mn);
      float rsum = p0 + p1;
#pragma unroll
      for (int off = 8; off > 0; off >>= 1) rsum += __shfl_xor(rsum, off);
      lrun[r] = lrun[r] * alpha[r] + rsum;
      mrun[r] = mn;
      ldsp[w][4 * g + r][lo] = f2bf(p0);
      ldsp[w][4 * g + r][16 + lo] = f2bf(p1);
    }
    if (__any(need)) {
      const f32x4 av = {alpha[0], alpha[1], alpha[2], alpha[3]};
#pragma unroll
      for (int ct = 0; ct < 8; ++ct) oacc[ct] *= av;
    }

    // ---- PV from LDS (8 MFMAs) ----
    const short8 pf = *(const short8*)&ldsp[w][lo][g * 8];
#pragma unroll
    for (int ct = 0; ct < 8; ++ct) {
      const int vrow = ct * 16 + lo;
      const short8 vf = *(const short8*)&lV[vrow * 32 + ((g ^ (lo & 3)) << 3)];
      oacc[ct] = MFMA16(pf, vf, oacc[ct]);
    }
  }

#pragma unroll
  for (int r = 0; r < 4; ++r) {
    const float inv = 1.f / lrun[r];
    const int row = qbase + 4 * g + r;
#pragma unroll
    for (int ct = 0; ct < 8; ++ct)
      Om[(size_t)row * D_DIM + hoff + ct * 16 + lo] = f2bf(oacc[ct][r] * inv);
  }
}

extern "C" void kernel_launch(void* const* d_in, const int* in_sizes, int n_in,
                              void* d_out, int out_size, void* d_ws, size_t ws_size,
                              hipStream_t stream) {
  const float* x    = (const float*)d_in[0];
  const float* wq   = (const float*)d_in[1];
  const float* bq   = (const float*)d_in[2];
  const float* wk   = (const float*)d_in[3];
  const float* bk   = (const float*)d_in[4];
  const float* wv   = (const float*)d_in[5];
  const float* bv   = (const float*)d_in[6];
  const float* wo   = (const float*)d_in[7];
  const float* bo   = (const float*)d_in[8];
  const float* gq   = (const float*)d_in[9];
  const float* gk   = (const float*)d_in[10];
  const float* cosT = (const float*)d_in[11];
  const float* sinT = (const float*)d_in[12];

  char* ws = (char*)d_ws;
  const size_t WB = (size_t)D_DIM * D_DIM * 2;
  const size_t XB = (size_t)S_LEN * D_DIM * 2;
  const size_t XF = (size_t)S_LEN * D_DIM * 4;
  u16*   wq_bf = (u16*)(ws);
  u16*   wk_bf = (u16*)(ws + WB);
  u16*   wv_bf = (u16*)(ws + 2 * WB);
  u16*   wo_bf = (u16*)(ws + 3 * WB);
  u16*   x_bf  = (u16*)(ws + 4 * WB);
  float* Q0    = (float*)(ws + 4 * WB + XB);
  float* K0    = (float*)(ws + 4 * WB + XB + XF);
  u16*   V0b   = (u16*)(ws + 4 * WB + XB + 2 * XF);
  // stream-ordered reuse:
  u16* q_bf = x_bf;
  u16* k_bf = wq_bf;
  u16* vT   = (u16*)Q0;
  u16* attn = (u16*)K0;

  const int nw4 = (D_DIM * D_DIM) / 4;
  const int nx4 = (S_LEN * D_DIM) / 4;
  k_cvt<<<nx4 / 256, 256, 0, stream>>>(x, x_bf, nx4);
  k_cvt_w<<<4 * nw4 / 256, 256, 0, stream>>>(wq, wk, wv, wo, wq_bf, wk_bf, wv_bf, wo_bf, nw4);

  k_gemm_qkv<<<1152, 256, 0, stream>>>(x_bf, wq_bf, wk_bf, wv_bf, bq, bk, bv, Q0, K0, V0b);

  k_rms_rope<<<S_LEN, 256, 0, stream>>>(Q0, gq, cosT, sinT, q_bf);
  k_rms_rope<<<S_LEN, 256, 0, stream>>>(K0, gk, cosT, sinT, k_bf);
  k_transpose<<<dim3(S_LEN / 64, D_DIM / 64), 256, 0, stream>>>(V0b, vT);

  k_attn3<<<dim3(S_LEN / 64, 16), 256, 0, stream>>>(q_bf, k_bf, vT, attn);

  k_gemm_nt<false><<<384, 256, 0, stream>>>(attn, wo_bf, bo, (float*)d_out, 24);
}